// Round 13
// baseline (126.400 us; speedup 1.0000x reference)
//
#include <hip/hip_runtime.h>
#include <hip/hip_fp16.h>

// ---------------------------------------------------------------------------
// TFN-lite layer, MI355X, round 21. Three dispatches:
//   memset(cnt) -> prep_all(table build | geometry scatter) -> tfn_node.
//
//  R21 vs R19 (125.8 us; prep_all now top kernel at ~45 us: build blocks
//  serialize build THEN scatter -> critical path = sum; absmax at TBL=8192
//  nearest was UNCHANGED vs lerp -> table step error is invisible):
//  * DISJOINT roles: blocks [0, TBL/RPB) do table build ONLY; blocks
//    [TBL/RPB, 2048) do the scatter ONLY. prep_all = max(build, scatter).
//  * TBL 8192 -> 4096: halves build, table 2.6 MB (L2-resident for node
//    gathers). Nearest step 2e-3; predicted absmax <= 0.13 (thr 0.3575).
//  * tfn_node: R19 verbatim (64-thr WG, grid=N, nearest-row 5x16B gather,
//    dot2 accumulate, reduce-scatter). Best-known shape.
// ---------------------------------------------------------------------------

#define INV_S3  0.5773502691896258f   // 1/sqrt(3)
#define A0S     0.1767766952966369f   // 1/sqrt(32)
#define A1S     0.27386127875258306f  // sqrt(3)/sqrt(40)
#define S15     3.872983346207417f    // sqrt(15)
#define S5      2.23606797749979f     // sqrt(5)
#define INV_S10 0.31622776601683794f  // 1/sqrt(10)   (cg121 normalized)
#define INV_S30 0.18257418583505536f  // 1/sqrt(30)

#define TBL   4096
#define RPB   16                      // table rows built per block
#define BBLK  (TBL / RPB)             // 256 build-only blocks
#define GRID  2048
#define DMAX  8.0f
#define CAP   64

typedef _Float16 half8 __attribute__((ext_vector_type(8)));
typedef _Float16 half2v __attribute__((ext_vector_type(2)));

// ---------------------------------------------------------------------------
// K1: blocks [0,BBLK) build 16 table rows each (W2 row values shared across
// 4 rows/thread); blocks [BBLK,GRID) grid-stride the geometry scatter.
__global__ __launch_bounds__(256) void prep_all(
    const float* __restrict__ W1, const float* __restrict__ W2,
    const int* __restrict__ ei, const float* __restrict__ pos,
    _Float16* __restrict__ T, int* __restrict__ cnt,
    float4* __restrict__ srec, int E) {

    __shared__ float hs[RPB][64];
    int tid = threadIdx.x;
    int wv = tid >> 6, lane = tid & 63;

    if (blockIdx.x < BBLK) {
        // ---------------- build only ----------------
        int jb = blockIdx.x * RPB;
        // phase A: each wave computes h for 4 rows (lane = hidden channel)
#pragma unroll
        for (int s = 0; s < 4; ++s) {
            int j = jb + wv * 4 + s;
            float d = (float)j * (DMAX / (float)(TBL - 1));
            float acc = 0.f;
#pragma unroll
            for (int i = 0; i < 16; ++i) {
                float t = d - (float)i * (1.0f / 3.0f);
                float r = __expf(-4.5f * t * t);
                acc = fmaf(r, W1[i * 64 + lane], acc);
            }
            hs[wv * 4 + s][lane] = fmaxf(acc, 0.f) * 0.25f;   // /sqrt(16)
        }
        __syncthreads();

        // phase B: wave wv folds W2 for its 4 rows; lane -> (u,wo)
        int u = lane >> 3, wo = lane & 7;
        int b0 = u * 16 + wo;
        int b4 = 512 + u * 8 + wo;
        float a0[4] = {0.f, 0.f, 0.f, 0.f};
        float a1[4] = {0.f, 0.f, 0.f, 0.f};
        float a2[4] = {0.f, 0.f, 0.f, 0.f};
        float a3[4] = {0.f, 0.f, 0.f, 0.f};
        float a4[4] = {0.f, 0.f, 0.f, 0.f};
#pragma unroll 2
        for (int k = 0; k < 64; ++k) {
            const float* Wk = W2 + k * 576;
            float w0 = Wk[b0]       + Wk[b0 + 8];
            float w1 = Wk[128 + b0] + Wk[128 + b0 + 8];
            float w2 = Wk[256 + b0] + Wk[256 + b0 + 8];
            float w3 = Wk[384 + b0] + Wk[384 + b0 + 8];
            float w4 = Wk[b4];
#pragma unroll
            for (int s = 0; s < 4; ++s) {
                float hk = hs[wv * 4 + s][k];
                a0[s] = fmaf(hk, w0, a0[s]);
                a1[s] = fmaf(hk, w1, a1[s]);
                a2[s] = fmaf(hk, w2, a2[s]);
                a3[s] = fmaf(hk, w3, a3[s]);
                a4[s] = fmaf(hk, w4, a4[s]);
            }
        }
        // Interleaved pair layout (R12): pair01 at u*16+wo*2, pair23 at +128,
        // w4 at 256+u*8+wo. Row stride 320 halfs (640 B).
#pragma unroll
        for (int s = 0; s < 4; ++s) {
            int j = jb + wv * 4 + s;
            _Float16* Tr = T + (size_t)j * 320;
            int base = u * 16 + wo * 2;
            Tr[base]             = (_Float16)a0[s];
            Tr[base + 1]         = (_Float16)a1[s];
            Tr[128 + base]       = (_Float16)a2[s];
            Tr[128 + base + 1]   = (_Float16)a3[s];
            Tr[256 + u * 8 + wo] = (_Float16)a4[s];
        }
    } else {
        // ---------------- scatter only ----------------
        int gtid = (blockIdx.x - BBLK) * 256 + tid;
        int gsz = (GRID - BBLK) * 256;
        for (int e = gtid; e < E; e += gsz) {
            int row = ei[e];
            int col = ei[E + e];
            float ax = pos[3 * row + 0] - pos[3 * col + 0];
            float ay = pos[3 * row + 1] - pos[3 * col + 1];
            float az = pos[3 * row + 2] - pos[3 * col + 2];
            float d2 = ax * ax + ay * ay + az * az + 1e-12f;
            float invd = rsqrtf(d2);
            float dd = d2 * invd;
            int p = atomicAdd(&cnt[row], 1);
            if (p < CAP) {
                float4 r;
                r.x = ax * invd;
                r.y = ay * invd;
                r.z = az * invd;
                r.w = dd;                         // raw fp32 d
                srec[(size_t)row * CAP + p] = r;
            }
        }
    }
}

// ---------------------------------------------------------------------------
// K2: one wave per block (64 thr), block n = node n (R19 verbatim).
// Nearest-row weights: j0 = round(fj); 5x16B gathers per edge-lane, no lerp.
__global__ __launch_bounds__(64) void tfn_node(
    const float* __restrict__ x, const float4* __restrict__ srec,
    const int* __restrict__ cnt, const _Float16* __restrict__ T,
    float* __restrict__ y, int N) {

    int lane = threadIdx.x & 63;
    int n = blockIdx.x;
    if (n >= N) return;

    int g = lane >> 3;
    int u = lane & 7;
    int kc = cnt[n];
    if (kc > CAP) kc = CAP;
    const float4* recs = srec + (size_t)n * CAP;

    const float* xr = x + (size_t)n * 32;
    float xu  = xr[u];
    float xv0 = xr[8 + 3 * u + 0];
    float xv1 = xr[8 + 3 * u + 1];
    float xv2 = xr[8 + 3 * u + 2];
    _Float16 xuh = (_Float16)xu;                    // loop-invariant coefs
    _Float16 p30 = (_Float16)(xv0 * INV_S3);
    _Float16 p31 = (_Float16)(xv1 * INV_S3);
    _Float16 p32 = (_Float16)(xv2 * INV_S3);

    // V: 32 output channels (final layout). V[z]=scalar z; vec w comp k -> V[8+3w+k].
    float V[32];
#pragma unroll
    for (int z = 0; z < 32; ++z) V[z] = 0.f;

    int rounds = (kc + 7) >> 3;
    float4 rec = make_float4(0.f, 0.f, 0.f, 0.f);
    if (rounds > 0) rec = recs[g];      // always-safe: CAP slots allocated
    for (int rd = 0; rd < rounds; ++rd) {
        float4 cur = rec;
        int slot = rd * 8 + g;
        if (rd + 1 < rounds) rec = recs[slot + 8];   // prefetch next round
        if (slot < kc) {
            float nx = cur.x, ny = cur.y, nz = cur.z;
            float dd = cur.w;

            float fj = dd * ((float)(TBL - 1) / DMAX);
            int j0 = (int)(fj + 0.5f);               // nearest row
            j0 = min(j0, TBL - 1);

            const _Float16* Ar = T + (size_t)j0 * 320;
            const _Float16* Au = Ar + u * 16;
            half8 w01a = *(const half8*)(Au);
            half8 w01b = *(const half8*)(Au + 8);
            half8 w23a = *(const half8*)(Au + 128);
            half8 w23b = *(const half8*)(Au + 136);
            half8 w4l  = *(const half8*)(Ar + 256 + u * 8);

            // geometry (per edge, per u) -- R12 verbatim
            float qu = xv0 * nx + xv1 * ny + xv2 * nz;   // (xv[u].Y1)/S3
            float Y22 = 0.5f * S5 * (3.f * ny * ny - 1.f);
            float Y24 = 0.5f * S15 * (nz * nz - nx * nx);
            float M00 = -Y22 * INV_S30 - Y24 * INV_S10;
            float M11 = 2.f * Y22 * INV_S30;
            float M22 = -Y22 * INV_S30 + Y24 * INV_S10;
            float M01 = (S15 * nx * ny) * INV_S10;
            float M02 = (S15 * nx * nz) * INV_S10;
            float M12 = (S15 * ny * nz) * INV_S10;
            float m0 = M00 * xv0 + M01 * xv1 + M02 * xv2;
            float m1 = M01 * xv0 + M11 * xv1 + M12 * xv2;
            float m2 = M02 * xv0 + M12 * xv1 + M22 * xv2;

            // packed coefficients
            half2v xq;  xq.x = xuh;  xq.y = (_Float16)qu;
            half2v c0;  c0.x = (_Float16)(xu * nx);  c0.y = p30;
            half2v c1;  c1.x = (_Float16)(xu * ny);  c1.y = p31;
            half2v c2;  c2.x = (_Float16)(xu * nz);  c2.y = p32;

            // t0+t1: V[z] += w0*xu + w1*qu   (one dot2 per z)
#pragma unroll
            for (int z = 0; z < 4; ++z) {
                half2v pa; pa.x = w01a[2 * z]; pa.y = w01a[2 * z + 1];
                V[z] = __builtin_amdgcn_fdot2(pa, xq, V[z], false);
                half2v pb; pb.x = w01b[2 * z]; pb.y = w01b[2 * z + 1];
                V[4 + z] = __builtin_amdgcn_fdot2(pb, xq, V[4 + z], false);
            }

            // t2+t3: V[8+3z+k] += w2*(xu*nk) + w3*(xvk/sqrt3)
#pragma unroll
            for (int z = 0; z < 4; ++z) {
                half2v pa; pa.x = w23a[2 * z]; pa.y = w23a[2 * z + 1];
                int b = 8 + 3 * z;
                V[b]     = __builtin_amdgcn_fdot2(pa, c0, V[b],     false);
                V[b + 1] = __builtin_amdgcn_fdot2(pa, c1, V[b + 1], false);
                V[b + 2] = __builtin_amdgcn_fdot2(pa, c2, V[b + 2], false);
                half2v pb; pb.x = w23b[2 * z]; pb.y = w23b[2 * z + 1];
                int b2 = 8 + 3 * (z + 4);
                V[b2]     = __builtin_amdgcn_fdot2(pb, c0, V[b2],     false);
                V[b2 + 1] = __builtin_amdgcn_fdot2(pb, c1, V[b2 + 1], false);
                V[b2 + 2] = __builtin_amdgcn_fdot2(pb, c2, V[b2 + 2], false);
            }

            // t4: f32 (precision-critical path)
#pragma unroll
            for (int z = 0; z < 8; ++z) {
                float we = (float)w4l[z];
                V[8 + 3 * z]  = fmaf(m0, we, V[8 + 3 * z]);
                V[9 + 3 * z]  = fmaf(m1, we, V[9 + 3 * z]);
                V[10 + 3 * z] = fmaf(m2, we, V[10 + 3 * z]);
            }
        }
    }

    // Recursive-halving reduce-scatter over lane bits 4..0 (32 shfls total).
#pragma unroll
    for (int h = 16; h >= 1; h >>= 1) {
        bool hi = (lane & h) != 0;
#pragma unroll
        for (int k = 0; k < h; ++k) {
            float lo = V[k], up = V[k + h];
            float keep = hi ? up : lo;
            float send = hi ? lo : up;
            V[k] = keep + __shfl_xor(send, h, 64);
        }
    }
    V[0] += __shfl_xor(V[0], 32, 64);

    if (lane < 32) {
        float v = V[0] * 0.125f * (lane < 8 ? A0S : A1S);
        if (lane < 8) v = v / (1.0f + __expf(-v));   // silu
        y[(size_t)n * 32 + lane] = v;
    }
}

// ---------------------------------------------------------------------------
extern "C" void kernel_launch(void* const* d_in, const int* in_sizes, int n_in,
                              void* d_out, int out_size, void* d_ws, size_t ws_size,
                              hipStream_t stream) {
    const float* x   = (const float*)d_in[0];
    const float* pos = (const float*)d_in[1];
    const int*   ei  = (const int*)d_in[2];
    const float* W1  = (const float*)d_in[3];
    const float* W2  = (const float*)d_in[4];
    int N = in_sizes[1] / 3;
    int E = in_sizes[2] / 2;

    char* ws = (char*)d_ws;
    size_t off = 0;
    _Float16* T    = (_Float16*)(ws + off); off += (size_t)TBL * 320 * 2;      // 2.62 MB
    int*      cnt  = (int*)(ws + off);      off += (size_t)N * 4;              // 100 KB
    float4*   srec = (float4*)(ws + off);   off += (size_t)N * CAP * 16;       // 25.6 MB

    float* y = (float*)d_out;

    hipMemsetAsync(cnt, 0, (size_t)N * 4, stream);
    hipLaunchKernelGGL(prep_all, dim3(GRID), dim3(256), 0, stream,
                       W1, W2, ei, pos, T, cnt, srec, E);
    hipLaunchKernelGGL(tfn_node, dim3(N), dim3(64), 0, stream,
                       x, srec, cnt, T, y, N);
}

// Round 14
// 124.413 us; speedup vs baseline: 1.0160x; 1.0160x over previous
//
#include <hip/hip_runtime.h>
#include <hip/hip_fp16.h>

// ---------------------------------------------------------------------------
// TFN-lite layer, MI355X, round 22. Three dispatches:
//   memset(cnt) -> prep_all(table build | geometry scatter) -> tfn_node.
//
//  R22 vs R21 (126.4 us; scatter identified as the ~45 us pole: 16B random
//  bucket writes -> 4.3x line amplification, WRITE 27.7MB @ ~700GB/s):
//  * 8-BYTE RECORDS: {nx,ny,nz,d} as 4xfp16 (uint2). Scatter payload 6.4->
//    3.2MB, dirty lines halve -> predicted WRITE ~14MB, prep_all ~30 us.
//    srec ws 25.6->12.8MB; K2 record FETCH halves.
//  * Precision (modeled, not bundled -- R7 lesson): fp16 RNE unit-vector
//    comps = 2.4e-4 rel on t1-t4 coef inputs; fp16 d -> delta-d ~2e-3 ~ 1
//    table row at TBL=4096, proven invisible (8192->4096 absmax unchanged
//    at 0.0625). Predicted absmax <= 0.15 vs thr 0.3575.
//  * K2 unpack = 2x __half22float2; all math downstream identical R21.
//  * Build path unchanged (TBL=4096, disjoint roles, RPB=16).
// ---------------------------------------------------------------------------

#define INV_S3  0.5773502691896258f   // 1/sqrt(3)
#define A0S     0.1767766952966369f   // 1/sqrt(32)
#define A1S     0.27386127875258306f  // sqrt(3)/sqrt(40)
#define S15     3.872983346207417f    // sqrt(15)
#define S5      2.23606797749979f     // sqrt(5)
#define INV_S10 0.31622776601683794f  // 1/sqrt(10)   (cg121 normalized)
#define INV_S30 0.18257418583505536f  // 1/sqrt(30)

#define TBL   4096
#define RPB   16                      // table rows built per block
#define BBLK  (TBL / RPB)             // 256 build-only blocks
#define GRID  2048
#define DMAX  8.0f
#define CAP   64

typedef _Float16 half8 __attribute__((ext_vector_type(8)));
typedef _Float16 half2v __attribute__((ext_vector_type(2)));

// ---------------------------------------------------------------------------
// K1: blocks [0,BBLK) build 16 table rows each; blocks [BBLK,GRID) grid-
// stride the geometry scatter with 8B packed records.
__global__ __launch_bounds__(256) void prep_all(
    const float* __restrict__ W1, const float* __restrict__ W2,
    const int* __restrict__ ei, const float* __restrict__ pos,
    _Float16* __restrict__ T, int* __restrict__ cnt,
    uint2* __restrict__ srec, int E) {

    __shared__ float hs[RPB][64];
    int tid = threadIdx.x;
    int wv = tid >> 6, lane = tid & 63;

    if (blockIdx.x < BBLK) {
        // ---------------- build only ----------------
        int jb = blockIdx.x * RPB;
#pragma unroll
        for (int s = 0; s < 4; ++s) {
            int j = jb + wv * 4 + s;
            float d = (float)j * (DMAX / (float)(TBL - 1));
            float acc = 0.f;
#pragma unroll
            for (int i = 0; i < 16; ++i) {
                float t = d - (float)i * (1.0f / 3.0f);
                float r = __expf(-4.5f * t * t);
                acc = fmaf(r, W1[i * 64 + lane], acc);
            }
            hs[wv * 4 + s][lane] = fmaxf(acc, 0.f) * 0.25f;   // /sqrt(16)
        }
        __syncthreads();

        int u = lane >> 3, wo = lane & 7;
        int b0 = u * 16 + wo;
        int b4 = 512 + u * 8 + wo;
        float a0[4] = {0.f, 0.f, 0.f, 0.f};
        float a1[4] = {0.f, 0.f, 0.f, 0.f};
        float a2[4] = {0.f, 0.f, 0.f, 0.f};
        float a3[4] = {0.f, 0.f, 0.f, 0.f};
        float a4[4] = {0.f, 0.f, 0.f, 0.f};
#pragma unroll 2
        for (int k = 0; k < 64; ++k) {
            const float* Wk = W2 + k * 576;
            float w0 = Wk[b0]       + Wk[b0 + 8];
            float w1 = Wk[128 + b0] + Wk[128 + b0 + 8];
            float w2 = Wk[256 + b0] + Wk[256 + b0 + 8];
            float w3 = Wk[384 + b0] + Wk[384 + b0 + 8];
            float w4 = Wk[b4];
#pragma unroll
            for (int s = 0; s < 4; ++s) {
                float hk = hs[wv * 4 + s][k];
                a0[s] = fmaf(hk, w0, a0[s]);
                a1[s] = fmaf(hk, w1, a1[s]);
                a2[s] = fmaf(hk, w2, a2[s]);
                a3[s] = fmaf(hk, w3, a3[s]);
                a4[s] = fmaf(hk, w4, a4[s]);
            }
        }
        // Interleaved pair layout: pair01 at u*16+wo*2, pair23 at +128,
        // w4 at 256+u*8+wo. Row stride 320 halfs (640 B).
#pragma unroll
        for (int s = 0; s < 4; ++s) {
            int j = jb + wv * 4 + s;
            _Float16* Tr = T + (size_t)j * 320;
            int base = u * 16 + wo * 2;
            Tr[base]             = (_Float16)a0[s];
            Tr[base + 1]         = (_Float16)a1[s];
            Tr[128 + base]       = (_Float16)a2[s];
            Tr[128 + base + 1]   = (_Float16)a3[s];
            Tr[256 + u * 8 + wo] = (_Float16)a4[s];
        }
    } else {
        // ---------------- scatter only (8B packed records) ----------------
        int gtid = (blockIdx.x - BBLK) * 256 + tid;
        int gsz = (GRID - BBLK) * 256;
        for (int e = gtid; e < E; e += gsz) {
            int row = ei[e];
            int col = ei[E + e];
            float ax = pos[3 * row + 0] - pos[3 * col + 0];
            float ay = pos[3 * row + 1] - pos[3 * col + 1];
            float az = pos[3 * row + 2] - pos[3 * col + 2];
            float d2 = ax * ax + ay * ay + az * az + 1e-12f;
            float invd = rsqrtf(d2);
            float dd = d2 * invd;
            int p = atomicAdd(&cnt[row], 1);
            if (p < CAP) {
                __half2 h0 = __floats2half2_rn(ax * invd, ay * invd);
                __half2 h1 = __floats2half2_rn(az * invd, dd);
                uint2 r;
                r.x = *(const unsigned*)&h0;
                r.y = *(const unsigned*)&h1;
                srec[(size_t)row * CAP + p] = r;
            }
        }
    }
}

// ---------------------------------------------------------------------------
// K2: one wave per block (64 thr), block n = node n (R21 shape).
// Nearest-row weights: j0 = round(fj); 5x16B gathers per edge-lane, no lerp.
__global__ __launch_bounds__(64) void tfn_node(
    const float* __restrict__ x, const uint2* __restrict__ srec,
    const int* __restrict__ cnt, const _Float16* __restrict__ T,
    float* __restrict__ y, int N) {

    int lane = threadIdx.x & 63;
    int n = blockIdx.x;
    if (n >= N) return;

    int g = lane >> 3;
    int u = lane & 7;
    int kc = cnt[n];
    if (kc > CAP) kc = CAP;
    const uint2* recs = srec + (size_t)n * CAP;

    const float* xr = x + (size_t)n * 32;
    float xu  = xr[u];
    float xv0 = xr[8 + 3 * u + 0];
    float xv1 = xr[8 + 3 * u + 1];
    float xv2 = xr[8 + 3 * u + 2];
    _Float16 xuh = (_Float16)xu;                    // loop-invariant coefs
    _Float16 p30 = (_Float16)(xv0 * INV_S3);
    _Float16 p31 = (_Float16)(xv1 * INV_S3);
    _Float16 p32 = (_Float16)(xv2 * INV_S3);

    // V: 32 output channels (final layout). V[z]=scalar z; vec w comp k -> V[8+3w+k].
    float V[32];
#pragma unroll
    for (int z = 0; z < 32; ++z) V[z] = 0.f;

    int rounds = (kc + 7) >> 3;
    uint2 rec = make_uint2(0u, 0u);
    if (rounds > 0) rec = recs[g];      // always-safe: CAP slots allocated
    for (int rd = 0; rd < rounds; ++rd) {
        uint2 cur = rec;
        int slot = rd * 8 + g;
        if (rd + 1 < rounds) rec = recs[slot + 8];   // prefetch next round
        if (slot < kc) {
            __half2 h0 = *(const __half2*)&cur.x;
            __half2 h1 = *(const __half2*)&cur.y;
            float2 f0 = __half22float2(h0);
            float2 f1 = __half22float2(h1);
            float nx = f0.x, ny = f0.y, nz = f1.x;
            float dd = f1.y;

            float fj = dd * ((float)(TBL - 1) / DMAX);
            int j0 = (int)(fj + 0.5f);               // nearest row
            j0 = min(j0, TBL - 1);

            const _Float16* Ar = T + (size_t)j0 * 320;
            const _Float16* Au = Ar + u * 16;
            half8 w01a = *(const half8*)(Au);
            half8 w01b = *(const half8*)(Au + 8);
            half8 w23a = *(const half8*)(Au + 128);
            half8 w23b = *(const half8*)(Au + 136);
            half8 w4l  = *(const half8*)(Ar + 256 + u * 8);

            // geometry (per edge, per u)
            float qu = xv0 * nx + xv1 * ny + xv2 * nz;   // (xv[u].Y1)/S3
            float Y22 = 0.5f * S5 * (3.f * ny * ny - 1.f);
            float Y24 = 0.5f * S15 * (nz * nz - nx * nx);
            float M00 = -Y22 * INV_S30 - Y24 * INV_S10;
            float M11 = 2.f * Y22 * INV_S30;
            float M22 = -Y22 * INV_S30 + Y24 * INV_S10;
            float M01 = (S15 * nx * ny) * INV_S10;
            float M02 = (S15 * nx * nz) * INV_S10;
            float M12 = (S15 * ny * nz) * INV_S10;
            float m0 = M00 * xv0 + M01 * xv1 + M02 * xv2;
            float m1 = M01 * xv0 + M11 * xv1 + M12 * xv2;
            float m2 = M02 * xv0 + M12 * xv1 + M22 * xv2;

            // packed coefficients
            half2v xq;  xq.x = xuh;  xq.y = (_Float16)qu;
            half2v c0;  c0.x = (_Float16)(xu * nx);  c0.y = p30;
            half2v c1;  c1.x = (_Float16)(xu * ny);  c1.y = p31;
            half2v c2;  c2.x = (_Float16)(xu * nz);  c2.y = p32;

            // t0+t1: V[z] += w0*xu + w1*qu   (one dot2 per z)
#pragma unroll
            for (int z = 0; z < 4; ++z) {
                half2v pa; pa.x = w01a[2 * z]; pa.y = w01a[2 * z + 1];
                V[z] = __builtin_amdgcn_fdot2(pa, xq, V[z], false);
                half2v pb; pb.x = w01b[2 * z]; pb.y = w01b[2 * z + 1];
                V[4 + z] = __builtin_amdgcn_fdot2(pb, xq, V[4 + z], false);
            }

            // t2+t3: V[8+3z+k] += w2*(xu*nk) + w3*(xvk/sqrt3)
#pragma unroll
            for (int z = 0; z < 4; ++z) {
                half2v pa; pa.x = w23a[2 * z]; pa.y = w23a[2 * z + 1];
                int b = 8 + 3 * z;
                V[b]     = __builtin_amdgcn_fdot2(pa, c0, V[b],     false);
                V[b + 1] = __builtin_amdgcn_fdot2(pa, c1, V[b + 1], false);
                V[b + 2] = __builtin_amdgcn_fdot2(pa, c2, V[b + 2], false);
                half2v pb; pb.x = w23b[2 * z]; pb.y = w23b[2 * z + 1];
                int b2 = 8 + 3 * (z + 4);
                V[b2]     = __builtin_amdgcn_fdot2(pb, c0, V[b2],     false);
                V[b2 + 1] = __builtin_amdgcn_fdot2(pb, c1, V[b2 + 1], false);
                V[b2 + 2] = __builtin_amdgcn_fdot2(pb, c2, V[b2 + 2], false);
            }

            // t4: f32 (precision-critical path)
#pragma unroll
            for (int z = 0; z < 8; ++z) {
                float we = (float)w4l[z];
                V[8 + 3 * z]  = fmaf(m0, we, V[8 + 3 * z]);
                V[9 + 3 * z]  = fmaf(m1, we, V[9 + 3 * z]);
                V[10 + 3 * z] = fmaf(m2, we, V[10 + 3 * z]);
            }
        }
    }

    // Recursive-halving reduce-scatter over lane bits 4..0 (32 shfls total).
#pragma unroll
    for (int h = 16; h >= 1; h >>= 1) {
        bool hi = (lane & h) != 0;
#pragma unroll
        for (int k = 0; k < h; ++k) {
            float lo = V[k], up = V[k + h];
            float keep = hi ? up : lo;
            float send = hi ? lo : up;
            V[k] = keep + __shfl_xor(send, h, 64);
        }
    }
    V[0] += __shfl_xor(V[0], 32, 64);

    if (lane < 32) {
        float v = V[0] * 0.125f * (lane < 8 ? A0S : A1S);
        if (lane < 8) v = v / (1.0f + __expf(-v));   // silu
        y[(size_t)n * 32 + lane] = v;
    }
}

// ---------------------------------------------------------------------------
extern "C" void kernel_launch(void* const* d_in, const int* in_sizes, int n_in,
                              void* d_out, int out_size, void* d_ws, size_t ws_size,
                              hipStream_t stream) {
    const float* x   = (const float*)d_in[0];
    const float* pos = (const float*)d_in[1];
    const int*   ei  = (const int*)d_in[2];
    const float* W1  = (const float*)d_in[3];
    const float* W2  = (const float*)d_in[4];
    int N = in_sizes[1] / 3;
    int E = in_sizes[2] / 2;

    char* ws = (char*)d_ws;
    size_t off = 0;
    _Float16* T    = (_Float16*)(ws + off); off += (size_t)TBL * 320 * 2;      // 2.62 MB
    int*      cnt  = (int*)(ws + off);      off += (size_t)N * 4;              // 100 KB
    uint2*    srec = (uint2*)(ws + off);    off += (size_t)N * CAP * 8;        // 12.8 MB

    float* y = (float*)d_out;

    hipMemsetAsync(cnt, 0, (size_t)N * 4, stream);
    hipLaunchKernelGGL(prep_all, dim3(GRID), dim3(256), 0, stream,
                       W1, W2, ei, pos, T, cnt, srec, E);
    hipLaunchKernelGGL(tfn_node, dim3(N), dim3(64), 0, stream,
                       x, srec, cnt, T, y, N);
}

// Round 15
// 121.564 us; speedup vs baseline: 1.0398x; 1.0234x over previous
//
#include <hip/hip_runtime.h>
#include <hip/hip_fp16.h>

// ---------------------------------------------------------------------------
// TFN-lite layer, MI355X, round 23. Three dispatches:
//   memset(cnt) -> prep_all(table build | geometry scatter) -> tfn_node.
//
//  R23 vs R22 (124.4 us; scatter constant ~44 us across grid/record/build
//  variations AND record-size halving moved WRITE by only 1.1MB -> the pole
//  is the cnt ATOMICS: 16 counters/64B line x 16 edges/counter = ~256
//  serialized far-RMWs per line at the coherence point ~ 40-60 us chain):
//  * PADDED COUNTERS: cnt[row] -> cnt[row*16] (one counter per 64B line).
//    Same-line serialization 256 -> ~16; consecutive rows spread across L3
//    slices. cnt region 100KB -> 1.6MB (memset +0.25us). Single-variable
//    change; all math verbatim R22 (absmax must stay exactly 0.0625).
// ---------------------------------------------------------------------------

#define INV_S3  0.5773502691896258f   // 1/sqrt(3)
#define A0S     0.1767766952966369f   // 1/sqrt(32)
#define A1S     0.27386127875258306f  // sqrt(3)/sqrt(40)
#define S15     3.872983346207417f    // sqrt(15)
#define S5      2.23606797749979f     // sqrt(5)
#define INV_S10 0.31622776601683794f  // 1/sqrt(10)   (cg121 normalized)
#define INV_S30 0.18257418583505536f  // 1/sqrt(30)

#define TBL   4096
#define RPB   16                      // table rows built per block
#define BBLK  (TBL / RPB)             // 256 build-only blocks
#define GRID  2048
#define DMAX  8.0f
#define CAP   64
#define CSTR  16                      // counter stride (ints) = 64B line

typedef _Float16 half8 __attribute__((ext_vector_type(8)));
typedef _Float16 half2v __attribute__((ext_vector_type(2)));

// ---------------------------------------------------------------------------
// K1: blocks [0,BBLK) build 16 table rows each; blocks [BBLK,GRID) grid-
// stride the geometry scatter with 8B packed records.
__global__ __launch_bounds__(256) void prep_all(
    const float* __restrict__ W1, const float* __restrict__ W2,
    const int* __restrict__ ei, const float* __restrict__ pos,
    _Float16* __restrict__ T, int* __restrict__ cnt,
    uint2* __restrict__ srec, int E) {

    __shared__ float hs[RPB][64];
    int tid = threadIdx.x;
    int wv = tid >> 6, lane = tid & 63;

    if (blockIdx.x < BBLK) {
        // ---------------- build only ----------------
        int jb = blockIdx.x * RPB;
#pragma unroll
        for (int s = 0; s < 4; ++s) {
            int j = jb + wv * 4 + s;
            float d = (float)j * (DMAX / (float)(TBL - 1));
            float acc = 0.f;
#pragma unroll
            for (int i = 0; i < 16; ++i) {
                float t = d - (float)i * (1.0f / 3.0f);
                float r = __expf(-4.5f * t * t);
                acc = fmaf(r, W1[i * 64 + lane], acc);
            }
            hs[wv * 4 + s][lane] = fmaxf(acc, 0.f) * 0.25f;   // /sqrt(16)
        }
        __syncthreads();

        int u = lane >> 3, wo = lane & 7;
        int b0 = u * 16 + wo;
        int b4 = 512 + u * 8 + wo;
        float a0[4] = {0.f, 0.f, 0.f, 0.f};
        float a1[4] = {0.f, 0.f, 0.f, 0.f};
        float a2[4] = {0.f, 0.f, 0.f, 0.f};
        float a3[4] = {0.f, 0.f, 0.f, 0.f};
        float a4[4] = {0.f, 0.f, 0.f, 0.f};
#pragma unroll 2
        for (int k = 0; k < 64; ++k) {
            const float* Wk = W2 + k * 576;
            float w0 = Wk[b0]       + Wk[b0 + 8];
            float w1 = Wk[128 + b0] + Wk[128 + b0 + 8];
            float w2 = Wk[256 + b0] + Wk[256 + b0 + 8];
            float w3 = Wk[384 + b0] + Wk[384 + b0 + 8];
            float w4 = Wk[b4];
#pragma unroll
            for (int s = 0; s < 4; ++s) {
                float hk = hs[wv * 4 + s][k];
                a0[s] = fmaf(hk, w0, a0[s]);
                a1[s] = fmaf(hk, w1, a1[s]);
                a2[s] = fmaf(hk, w2, a2[s]);
                a3[s] = fmaf(hk, w3, a3[s]);
                a4[s] = fmaf(hk, w4, a4[s]);
            }
        }
        // Interleaved pair layout: pair01 at u*16+wo*2, pair23 at +128,
        // w4 at 256+u*8+wo. Row stride 320 halfs (640 B).
#pragma unroll
        for (int s = 0; s < 4; ++s) {
            int j = jb + wv * 4 + s;
            _Float16* Tr = T + (size_t)j * 320;
            int base = u * 16 + wo * 2;
            Tr[base]             = (_Float16)a0[s];
            Tr[base + 1]         = (_Float16)a1[s];
            Tr[128 + base]       = (_Float16)a2[s];
            Tr[128 + base + 1]   = (_Float16)a3[s];
            Tr[256 + u * 8 + wo] = (_Float16)a4[s];
        }
    } else {
        // ---------------- scatter only (8B packed records) ----------------
        int gtid = (blockIdx.x - BBLK) * 256 + tid;
        int gsz = (GRID - BBLK) * 256;
        for (int e = gtid; e < E; e += gsz) {
            int row = ei[e];
            int col = ei[E + e];
            float ax = pos[3 * row + 0] - pos[3 * col + 0];
            float ay = pos[3 * row + 1] - pos[3 * col + 1];
            float az = pos[3 * row + 2] - pos[3 * col + 2];
            float d2 = ax * ax + ay * ay + az * az + 1e-12f;
            float invd = rsqrtf(d2);
            float dd = d2 * invd;
            int p = atomicAdd(&cnt[(size_t)row * CSTR], 1);
            if (p < CAP) {
                __half2 h0 = __floats2half2_rn(ax * invd, ay * invd);
                __half2 h1 = __floats2half2_rn(az * invd, dd);
                uint2 r;
                r.x = *(const unsigned*)&h0;
                r.y = *(const unsigned*)&h1;
                srec[(size_t)row * CAP + p] = r;
            }
        }
    }
}

// ---------------------------------------------------------------------------
// K2: one wave per block (64 thr), block n = node n (R22 verbatim except
// padded-counter read). Nearest-row weights: j0 = round(fj); 5x16B gathers.
__global__ __launch_bounds__(64) void tfn_node(
    const float* __restrict__ x, const uint2* __restrict__ srec,
    const int* __restrict__ cnt, const _Float16* __restrict__ T,
    float* __restrict__ y, int N) {

    int lane = threadIdx.x & 63;
    int n = blockIdx.x;
    if (n >= N) return;

    int g = lane >> 3;
    int u = lane & 7;
    int kc = cnt[(size_t)n * CSTR];
    if (kc > CAP) kc = CAP;
    const uint2* recs = srec + (size_t)n * CAP;

    const float* xr = x + (size_t)n * 32;
    float xu  = xr[u];
    float xv0 = xr[8 + 3 * u + 0];
    float xv1 = xr[8 + 3 * u + 1];
    float xv2 = xr[8 + 3 * u + 2];
    _Float16 xuh = (_Float16)xu;                    // loop-invariant coefs
    _Float16 p30 = (_Float16)(xv0 * INV_S3);
    _Float16 p31 = (_Float16)(xv1 * INV_S3);
    _Float16 p32 = (_Float16)(xv2 * INV_S3);

    // V: 32 output channels (final layout). V[z]=scalar z; vec w comp k -> V[8+3w+k].
    float V[32];
#pragma unroll
    for (int z = 0; z < 32; ++z) V[z] = 0.f;

    int rounds = (kc + 7) >> 3;
    uint2 rec = make_uint2(0u, 0u);
    if (rounds > 0) rec = recs[g];      // always-safe: CAP slots allocated
    for (int rd = 0; rd < rounds; ++rd) {
        uint2 cur = rec;
        int slot = rd * 8 + g;
        if (rd + 1 < rounds) rec = recs[slot + 8];   // prefetch next round
        if (slot < kc) {
            __half2 h0 = *(const __half2*)&cur.x;
            __half2 h1 = *(const __half2*)&cur.y;
            float2 f0 = __half22float2(h0);
            float2 f1 = __half22float2(h1);
            float nx = f0.x, ny = f0.y, nz = f1.x;
            float dd = f1.y;

            float fj = dd * ((float)(TBL - 1) / DMAX);
            int j0 = (int)(fj + 0.5f);               // nearest row
            j0 = min(j0, TBL - 1);

            const _Float16* Ar = T + (size_t)j0 * 320;
            const _Float16* Au = Ar + u * 16;
            half8 w01a = *(const half8*)(Au);
            half8 w01b = *(const half8*)(Au + 8);
            half8 w23a = *(const half8*)(Au + 128);
            half8 w23b = *(const half8*)(Au + 136);
            half8 w4l  = *(const half8*)(Ar + 256 + u * 8);

            // geometry (per edge, per u)
            float qu = xv0 * nx + xv1 * ny + xv2 * nz;   // (xv[u].Y1)/S3
            float Y22 = 0.5f * S5 * (3.f * ny * ny - 1.f);
            float Y24 = 0.5f * S15 * (nz * nz - nx * nx);
            float M00 = -Y22 * INV_S30 - Y24 * INV_S10;
            float M11 = 2.f * Y22 * INV_S30;
            float M22 = -Y22 * INV_S30 + Y24 * INV_S10;
            float M01 = (S15 * nx * ny) * INV_S10;
            float M02 = (S15 * nx * nz) * INV_S10;
            float M12 = (S15 * ny * nz) * INV_S10;
            float m0 = M00 * xv0 + M01 * xv1 + M02 * xv2;
            float m1 = M01 * xv0 + M11 * xv1 + M12 * xv2;
            float m2 = M02 * xv0 + M12 * xv1 + M22 * xv2;

            // packed coefficients
            half2v xq;  xq.x = xuh;  xq.y = (_Float16)qu;
            half2v c0;  c0.x = (_Float16)(xu * nx);  c0.y = p30;
            half2v c1;  c1.x = (_Float16)(xu * ny);  c1.y = p31;
            half2v c2;  c2.x = (_Float16)(xu * nz);  c2.y = p32;

            // t0+t1: V[z] += w0*xu + w1*qu   (one dot2 per z)
#pragma unroll
            for (int z = 0; z < 4; ++z) {
                half2v pa; pa.x = w01a[2 * z]; pa.y = w01a[2 * z + 1];
                V[z] = __builtin_amdgcn_fdot2(pa, xq, V[z], false);
                half2v pb; pb.x = w01b[2 * z]; pb.y = w01b[2 * z + 1];
                V[4 + z] = __builtin_amdgcn_fdot2(pb, xq, V[4 + z], false);
            }

            // t2+t3: V[8+3z+k] += w2*(xu*nk) + w3*(xvk/sqrt3)
#pragma unroll
            for (int z = 0; z < 4; ++z) {
                half2v pa; pa.x = w23a[2 * z]; pa.y = w23a[2 * z + 1];
                int b = 8 + 3 * z;
                V[b]     = __builtin_amdgcn_fdot2(pa, c0, V[b],     false);
                V[b + 1] = __builtin_amdgcn_fdot2(pa, c1, V[b + 1], false);
                V[b + 2] = __builtin_amdgcn_fdot2(pa, c2, V[b + 2], false);
                half2v pb; pb.x = w23b[2 * z]; pb.y = w23b[2 * z + 1];
                int b2 = 8 + 3 * (z + 4);
                V[b2]     = __builtin_amdgcn_fdot2(pb, c0, V[b2],     false);
                V[b2 + 1] = __builtin_amdgcn_fdot2(pb, c1, V[b2 + 1], false);
                V[b2 + 2] = __builtin_amdgcn_fdot2(pb, c2, V[b2 + 2], false);
            }

            // t4: f32 (precision-critical path)
#pragma unroll
            for (int z = 0; z < 8; ++z) {
                float we = (float)w4l[z];
                V[8 + 3 * z]  = fmaf(m0, we, V[8 + 3 * z]);
                V[9 + 3 * z]  = fmaf(m1, we, V[9 + 3 * z]);
                V[10 + 3 * z] = fmaf(m2, we, V[10 + 3 * z]);
            }
        }
    }

    // Recursive-halving reduce-scatter over lane bits 4..0 (32 shfls total).
#pragma unroll
    for (int h = 16; h >= 1; h >>= 1) {
        bool hi = (lane & h) != 0;
#pragma unroll
        for (int k = 0; k < h; ++k) {
            float lo = V[k], up = V[k + h];
            float keep = hi ? up : lo;
            float send = hi ? lo : up;
            V[k] = keep + __shfl_xor(send, h, 64);
        }
    }
    V[0] += __shfl_xor(V[0], 32, 64);

    if (lane < 32) {
        float v = V[0] * 0.125f * (lane < 8 ? A0S : A1S);
        if (lane < 8) v = v / (1.0f + __expf(-v));   // silu
        y[(size_t)n * 32 + lane] = v;
    }
}

// ---------------------------------------------------------------------------
extern "C" void kernel_launch(void* const* d_in, const int* in_sizes, int n_in,
                              void* d_out, int out_size, void* d_ws, size_t ws_size,
                              hipStream_t stream) {
    const float* x   = (const float*)d_in[0];
    const float* pos = (const float*)d_in[1];
    const int*   ei  = (const int*)d_in[2];
    const float* W1  = (const float*)d_in[3];
    const float* W2  = (const float*)d_in[4];
    int N = in_sizes[1] / 3;
    int E = in_sizes[2] / 2;

    char* ws = (char*)d_ws;
    size_t off = 0;
    _Float16* T    = (_Float16*)(ws + off); off += (size_t)TBL * 320 * 2;      // 2.62 MB
    int*      cnt  = (int*)(ws + off);      off += (size_t)N * CSTR * 4;       // 1.6 MB
    uint2*    srec = (uint2*)(ws + off);    off += (size_t)N * CAP * 8;        // 12.8 MB

    float* y = (float*)d_out;

    hipMemsetAsync(cnt, 0, (size_t)N * CSTR * 4, stream);
    hipLaunchKernelGGL(prep_all, dim3(GRID), dim3(256), 0, stream,
                       W1, W2, ei, pos, T, cnt, srec, E);
    hipLaunchKernelGGL(tfn_node, dim3(N), dim3(64), 0, stream,
                       x, srec, cnt, T, y, N);
}